// Round 2
// baseline (3590.710 us; speedup 1.0000x reference)
//
#include <hip/hip_runtime.h>
#include <math.h>

// Problem dims
#define NB   16     // batch
#define SL   128    // seq len
#define ED   300    // word emb dim
#define HD   512    // lstm hidden
#define G4   2048   // 4*HD
#define NT   9      // tag count T
#define BE   64     // bio emb dim
#define RE   128    // REL_E
#define NR   50     // R
#define OCD  576    // HD + BE
#define NTOK 2048   // NB*SL

__device__ __forceinline__ float sigf(float x){ return 1.0f/(1.0f + __expf(-x)); }

// ---------------------------------------------------------------- gather emb
__global__ __launch_bounds__(256) void gather_emb_k(const int* __restrict__ tokens,
                                                    const float* __restrict__ word_emb,
                                                    float* __restrict__ emb)
{
    int idx = blockIdx.x*256 + threadIdx.x;
    if (idx < NTOK*ED){
        int row = idx / ED;
        int k = idx - row*ED;
        emb[idx] = word_emb[tokens[row]*ED + k];
    }
}

// ---------------------------------------------------------------- generic fp32 GEMM
// C[m,n] = act( sum_k A[m,k]*B[n,k] + bias1[n] + bias2[n] )
template<int TM>
__global__ __launch_bounds__(256) void gemm_k(const float* __restrict__ A, int lda,
                                              const float* __restrict__ Bm, int ldb,
                                              float* __restrict__ C, int ldc,
                                              int N, int K,
                                              const float* __restrict__ bias1,
                                              const float* __restrict__ bias2,
                                              int do_relu)
{
    constexpr int TR = TM/16;                 // rows per thread (8 or 4)
    __shared__ float As[16][TM+4];            // [k][m]
    __shared__ float Bs[16][68];              // [k][n]
    const int t = threadIdx.x;
    const int m_blk = blockIdx.x * TM;
    const int n_blk = blockIdx.y * 64;
    const int tm = (t >> 4) * TR;
    const int tn = (t & 15) * 4;
    float acc[TR][4];
    #pragma unroll
    for (int i=0;i<TR;++i){ acc[i][0]=0.f; acc[i][1]=0.f; acc[i][2]=0.f; acc[i][3]=0.f; }

    const int kc = (K + 15) >> 4;
    for (int ck = 0; ck < kc; ++ck){
        const int k0 = ck << 4;
        __syncthreads();
        #pragma unroll
        for (int it = 0; it < TM/64; ++it){
            int task = t + it*256;
            int m = task >> 2, q = task & 3;
            int kk = k0 + q*4;
            float4 v = make_float4(0.f,0.f,0.f,0.f);
            const float* ap = A + (size_t)(m_blk + m)*lda + kk;
            if (kk + 3 < K) v = *(const float4*)ap;
            else {
                if (kk   < K) v.x = ap[0];
                if (kk+1 < K) v.y = ap[1];
                if (kk+2 < K) v.z = ap[2];
            }
            As[q*4+0][m] = v.x; As[q*4+1][m] = v.y; As[q*4+2][m] = v.z; As[q*4+3][m] = v.w;
        }
        {
            int n = t >> 2, q = t & 3;
            int kk = k0 + q*4;
            int gn = n_blk + n;
            float4 v = make_float4(0.f,0.f,0.f,0.f);
            if (gn < N){
                const float* bp = Bm + (size_t)gn*ldb + kk;
                if (kk + 3 < K) v = *(const float4*)bp;
                else {
                    if (kk   < K) v.x = bp[0];
                    if (kk+1 < K) v.y = bp[1];
                    if (kk+2 < K) v.z = bp[2];
                }
            }
            Bs[q*4+0][n] = v.x; Bs[q*4+1][n] = v.y; Bs[q*4+2][n] = v.z; Bs[q*4+3][n] = v.w;
        }
        __syncthreads();
        #pragma unroll
        for (int k = 0; k < 16; ++k){
            float4 b4 = *(const float4*)&Bs[k][tn];
            float bn[4] = {b4.x, b4.y, b4.z, b4.w};
            #pragma unroll
            for (int i = 0; i < TR/4; ++i){
                float4 a4 = *(const float4*)&As[k][tm + i*4];
                float am[4] = {a4.x, a4.y, a4.z, a4.w};
                #pragma unroll
                for (int mm = 0; mm < 4; ++mm){
                    #pragma unroll
                    for (int nn = 0; nn < 4; ++nn)
                        acc[i*4+mm][nn] += am[mm]*bn[nn];
                }
            }
        }
    }
    float bv[4];
    #pragma unroll
    for (int nn=0;nn<4;++nn){
        int gn = n_blk + tn + nn;
        float bb = 0.f;
        if (gn < N){
            if (bias1) bb += bias1[gn];
            if (bias2) bb += bias2[gn];
        }
        bv[nn] = bb;
    }
    bool vec = ((ldc & 3) == 0) && (n_blk + tn + 3 < N);
    #pragma unroll
    for (int mm = 0; mm < TR; ++mm){
        int gm = m_blk + tm + mm;
        float r0 = acc[mm][0] + bv[0];
        float r1 = acc[mm][1] + bv[1];
        float r2 = acc[mm][2] + bv[2];
        float r3 = acc[mm][3] + bv[3];
        if (do_relu){ r0=fmaxf(r0,0.f); r1=fmaxf(r1,0.f); r2=fmaxf(r2,0.f); r3=fmaxf(r3,0.f); }
        if (vec){
            *(float4*)(C + (size_t)gm*ldc + n_blk + tn) = make_float4(r0,r1,r2,r3);
        } else {
            int gn = n_blk + tn;
            if (gn   < N) C[(size_t)gm*ldc + gn  ] = r0;
            if (gn+1 < N) C[(size_t)gm*ldc + gn+1] = r1;
            if (gn+2 < N) C[(size_t)gm*ldc + gn+2] = r2;
            if (gn+3 < N) C[(size_t)gm*ldc + gn+3] = r3;
        }
    }
}

// ---------------------------------------------------------------- persistent LSTM
// 256 workgroups (cooperative): wg -> (dir d = wg&1, hidden-group hg = wg>>1).
// Weights (16 gate rows x 512) in registers. One contention-free grid barrier per
// timestep PER DIRECTION: each wg release-stores an arrival flag to its own padded
// cacheline; aggregator wg (wg 0 for dir 0, wg 1 for dir 1) polls its direction's
// 128 flags with one wave + __all, then release-stores go[s,d]; other wgs poll go
// read-only. No RMW, no shared-line stores (fix for R1's 17us/step barrier).
// h exchanged via global double buffer with agent-scope atomics (XCD non-coherence).
__global__ __launch_bounds__(256) void lstm_k(const float* __restrict__ xwf,
                                              const float* __restrict__ xwb,
                                              const float* __restrict__ whhf,
                                              const float* __restrict__ whhb,
                                              float* __restrict__ hbuf,     // 4 * NB*HD
                                              float* __restrict__ hf_all,
                                              float* __restrict__ hb_all,
                                              unsigned int* __restrict__ arrive,  // SL*256*4
                                              unsigned int* __restrict__ go)      // SL*2*4
{
    __shared__ __align__(16) float h_s[NB*HD];   // 32 KB
    __shared__ float part[16*257];               // 16.4 KB
    __shared__ float gates_s[256];
    __shared__ float cst[64];
    const int wg = blockIdx.x;
    const int d  = wg & 1;
    const int hg = wg >> 1;                       // 0..127
    const int t  = threadIdx.x;
    const float* whh = d ? whhb : whhf;
    const float* xw  = d ? xwb  : xwf;
    float* hall      = d ? hb_all : hf_all;

    const int c   = t >> 3;                       // k-chunk 0..31 (16 k each)
    const int rp  = t & 7;                        // row pair
    const int lr0 = rp*2, lr1 = rp*2 + 1;         // local rows (g*4 + hl)
    const int col0 = ((lr0 >> 2) << 9) + (hg << 2) + (lr0 & 3);
    const int col1 = ((lr1 >> 2) << 9) + (hg << 2) + (lr1 & 3);
    float4 w0v[4], w1v[4];
    #pragma unroll
    for (int q=0;q<4;++q){
        w0v[q] = *(const float4*)(whh + (size_t)col0*HD + c*16 + q*4);
        w1v[q] = *(const float4*)(whh + (size_t)col1*HD + c*16 + q*4);
    }
    const int rb  = t >> 4;
    const int rlr = t & 15;
    const int rcol = ((rlr >> 2) << 9) + (hg << 2) + (rlr & 3);
    const int ab = t >> 2, ahl = t & 3;

    if (t < 64){
        cst[t] = 0.f;
        __hip_atomic_store(&hbuf[(d*2+0)*(NB*HD) + ab*HD + (hg<<2) + ahl], 0.f,
                           __ATOMIC_RELAXED, __HIP_MEMORY_SCOPE_AGENT);
    }

    for (int s = 0; s < SL; ++s){
        __syncthreads();  // all prior agent-scope h stores issued by this wg are drained
        // ---- contention-free per-direction grid barrier ----
        if (t == 0){
            __hip_atomic_store(&arrive[(s*256 + wg)*4], 1u,
                               __ATOMIC_RELEASE, __HIP_MEMORY_SCOPE_AGENT);
        }
        if (wg < 2){
            // aggregator for direction d (== wg): wave 0 polls this dir's 128 flags
            if (t < 64){
                const unsigned int* af = arrive + (size_t)s*256*4;
                const int i0 = (t*2 + d)*4;
                const int i1 = ((t+64)*2 + d)*4;
                for (;;){
                    unsigned int f0 = __hip_atomic_load(&af[i0], __ATOMIC_ACQUIRE, __HIP_MEMORY_SCOPE_AGENT);
                    unsigned int f1 = __hip_atomic_load(&af[i1], __ATOMIC_ACQUIRE, __HIP_MEMORY_SCOPE_AGENT);
                    if (__all(f0 != 0u && f1 != 0u)) break;
                    __builtin_amdgcn_s_sleep(1);
                }
                if (t == 0)
                    __hip_atomic_store(&go[(s*2 + d)*4], 1u,
                                       __ATOMIC_RELEASE, __HIP_MEMORY_SCOPE_AGENT);
            }
        } else {
            if (t == 0){
                while (__hip_atomic_load(&go[(s*2 + d)*4], __ATOMIC_ACQUIRE, __HIP_MEMORY_SCOPE_AGENT) == 0u)
                    __builtin_amdgcn_s_sleep(1);
            }
        }
        __syncthreads();
        // ---- stage h (this direction) into LDS ----
        {
            const unsigned long long* src = (const unsigned long long*)(hbuf + (d*2 + (s&1))*(NB*HD));
            unsigned long long* dst = (unsigned long long*)h_s;
            #pragma unroll
            for (int i = 0; i < 16; ++i){
                dst[i*256 + t] = __hip_atomic_load(&src[i*256 + t], __ATOMIC_RELAXED, __HIP_MEMORY_SCOPE_AGENT);
            }
        }
        const int tx = d ? (SL-1 - s) : s;
        const float xval = xw[(size_t)(rb*SL + tx)*G4 + rcol];
        __syncthreads();
        // ---- partial dot products ----
        #pragma unroll 2
        for (int b = 0; b < NB; ++b){
            const float4* hp = (const float4*)(h_s + b*HD + c*16);
            float4 h0 = hp[0], h1 = hp[1], h2 = hp[2], h3 = hp[3];
            float p0 = w0v[0].x*h0.x + w0v[0].y*h0.y + w0v[0].z*h0.z + w0v[0].w*h0.w
                     + w0v[1].x*h1.x + w0v[1].y*h1.y + w0v[1].z*h1.z + w0v[1].w*h1.w
                     + w0v[2].x*h2.x + w0v[2].y*h2.y + w0v[2].z*h2.z + w0v[2].w*h2.w
                     + w0v[3].x*h3.x + w0v[3].y*h3.y + w0v[3].z*h3.z + w0v[3].w*h3.w;
            float p1 = w1v[0].x*h0.x + w1v[0].y*h0.y + w1v[0].z*h0.z + w1v[0].w*h0.w
                     + w1v[1].x*h1.x + w1v[1].y*h1.y + w1v[1].z*h1.z + w1v[1].w*h1.w
                     + w1v[2].x*h2.x + w1v[2].y*h2.y + w1v[2].z*h2.z + w1v[2].w*h2.w
                     + w1v[3].x*h3.x + w1v[3].y*h3.y + w1v[3].z*h3.z + w1v[3].w*h3.w;
            p0 += __shfl_xor(p0, 8);
            p1 += __shfl_xor(p1, 8);
            if ((c & 1) == 0){
                const int ch = c >> 1;
                part[ch*257 + b*16 + lr0] = p0;
                part[ch*257 + b*16 + lr1] = p1;
            }
        }
        __syncthreads();
        {
            float ssum = 0.f;
            #pragma unroll
            for (int ch = 0; ch < 16; ++ch) ssum += part[ch*257 + t];
            gates_s[t] = ssum + xval;
        }
        __syncthreads();
        if (t < 64){
            float gi = gates_s[ab*16 + 0  + ahl];
            float gf = gates_s[ab*16 + 4  + ahl];
            float gg = gates_s[ab*16 + 8  + ahl];
            float go_ = gates_s[ab*16 + 12 + ahl];
            float cp = cst[t];
            float cn = sigf(gf)*cp + sigf(gi)*tanhf(gg);
            float hn = sigf(go_)*tanhf(cn);
            cst[t] = cn;
            const int hid = (hg<<2) + ahl;
            __hip_atomic_store(&hbuf[(d*2 + ((s+1)&1))*(NB*HD) + ab*HD + hid], hn,
                               __ATOMIC_RELAXED, __HIP_MEMORY_SCOPE_AGENT);
            hall[(size_t)(ab*SL + tx)*HD + hid] = hn;
        }
    }
}

// ---------------------------------------------------------------- combine o | bio_emb
__global__ __launch_bounds__(256) void combine_k(const float* __restrict__ hf,
                                                 const float* __restrict__ hb,
                                                 const int* __restrict__ bio_gold,
                                                 const float* __restrict__ bio_emb,
                                                 float* __restrict__ oc)
{
    int idx = blockIdx.x*256 + threadIdx.x;      // float4 index over NTOK*144
    if (idx >= NTOK*144) return;
    int row = idx / 144;
    int c4 = (idx - row*144) * 4;
    float4 v;
    if (c4 < HD){
        float4 a = *(const float4*)(hf + (size_t)row*HD + c4);
        float4 b = *(const float4*)(hb + (size_t)row*HD + c4);
        v = make_float4(0.5f*(a.x+b.x), 0.5f*(a.y+b.y), 0.5f*(a.z+b.z), 0.5f*(a.w+b.w));
    } else {
        int bg = bio_gold[row];
        v = *(const float4*)(bio_emb + bg*BE + (c4 - HD));
    }
    *(float4*)(oc + (size_t)row*OCD + c4) = v;
}

// ---------------------------------------------------------------- CRF NLL
__global__ __launch_bounds__(64) void crf_k(const float* __restrict__ emi,
                                            const int* __restrict__ tags,
                                            const int* __restrict__ tokens,
                                            const float* __restrict__ trans,
                                            const float* __restrict__ startv,
                                            const float* __restrict__ endv,
                                            float* __restrict__ out_crf)
{
    __shared__ float al[16];
    const int b = blockIdx.x, lane = threadIdx.x;
    unsigned long long m0 = __ballot(tokens[b*SL + lane] != 0);
    unsigned long long m1 = __ballot(tokens[b*SL + 64 + lane] != 0);
    const int len = __popcll(m0) + __popcll(m1);
    float npart = 0.f;
    #pragma unroll
    for (int half = 0; half < 2; ++half){
        int tt = lane + half*64;
        if (tt >= 1 && tt < len){
            int tp = tags[b*SL + tt - 1], tc = tags[b*SL + tt];
            npart += trans[tp*NT + tc] + emi[(size_t)(b*SL + tt)*NT + tc];
        }
    }
    #pragma unroll
    for (int off = 32; off > 0; off >>= 1) npart += __shfl_down(npart, off);
    float tr[NT]; float alpha = -1e30f;
    if (lane < NT){
        #pragma unroll
        for (int i = 0; i < NT; ++i) tr[i] = trans[i*NT + lane];
        alpha = startv[lane] + emi[(size_t)(b*SL)*NT + lane];
    }
    for (int tt = 1; tt < SL; ++tt){
        if (lane < NT) al[lane] = alpha;
        __syncthreads();
        if (lane < NT && tt < len){
            float mx = -1e30f;
            #pragma unroll
            for (int i = 0; i < NT; ++i) mx = fmaxf(mx, al[i] + tr[i]);
            float se = 0.f;
            #pragma unroll
            for (int i = 0; i < NT; ++i) se += __expf(al[i] + tr[i] - mx);
            alpha = mx + __logf(se) + emi[(size_t)(b*SL + tt)*NT + lane];
        }
        __syncthreads();
    }
    if (lane < NT) al[lane] = alpha + endv[lane];
    __syncthreads();
    if (lane == 0){
        float mx = -1e30f;
        for (int i = 0; i < NT; ++i) mx = fmaxf(mx, al[i]);
        float se = 0.f;
        for (int i = 0; i < NT; ++i) se += __expf(al[i] - mx);
        float den = mx + __logf(se);
        int t0g = tags[b*SL];
        float num = startv[t0g] + emi[(size_t)(b*SL)*NT + t0g] + npart;
        num += endv[tags[b*SL + len - 1]];
        atomicAdd(out_crf, -(num - den) * (1.0f/16.0f));
    }
}

// ---------------------------------------------------------------- token count
__global__ __launch_bounds__(256) void msum_k(const int* __restrict__ tokens, float* __restrict__ out_m)
{
    __shared__ int rr[4];
    int t = threadIdx.x;
    int cnt = 0;
    for (int i = t; i < NTOK; i += 256) cnt += (tokens[i] != 0) ? 1 : 0;
    #pragma unroll
    for (int off = 32; off > 0; off >>= 1) cnt += __shfl_down(cnt, off);
    if ((t & 63) == 0) rr[t >> 6] = cnt;
    __syncthreads();
    if (t == 0) out_m[0] = (float)(rr[0]+rr[1]+rr[2]+rr[3]);
}

// ---------------------------------------------------------------- fused uv->logits->BCE
__global__ __launch_bounds__(256) void sel_k(const float* __restrict__ U2,
                                             const float* __restrict__ V2,
                                             const float* __restrict__ uvb,
                                             const float* __restrict__ rel_emb,
                                             const int* __restrict__ gold,
                                             const int* __restrict__ tokens,
                                             float* __restrict__ out_sel)
{
    __shared__ float ret_s[RE][52];   // [k][r]
    __shared__ float pt_s[RE][68];    // [k][j]
    __shared__ float vb_s[RE];
    __shared__ float mk_s[64];
    __shared__ float red_s[4];
    const int jt = blockIdx.x, qi = blockIdx.y, b = blockIdx.z;
    const int t = threadIdx.x;
    if (tokens[b*SL + qi] == 0) return;   // pm row entirely zero
    if (t < 32){
        float4 v4 = *(const float4*)(V2 + (size_t)(b*SL + qi)*RE + t*4);
        float4 b4 = *(const float4*)(uvb + t*4);
        vb_s[t*4+0] = v4.x + b4.x; vb_s[t*4+1] = v4.y + b4.y;
        vb_s[t*4+2] = v4.z + b4.z; vb_s[t*4+3] = v4.w + b4.w;
    }
    if (t < 64) mk_s[t] = (tokens[b*SL + jt*64 + t] != 0) ? 1.f : 0.f;
    {
        int r = t & 63;
        for (int q = t >> 6; q < 32; q += 4){
            if (r < NR){
                float4 e4 = *(const float4*)(rel_emb + (size_t)r*RE + q*4);
                ret_s[q*4+0][r] = e4.x; ret_s[q*4+1][r] = e4.y;
                ret_s[q*4+2][r] = e4.z; ret_s[q*4+3][r] = e4.w;
            } else if (r < 64){
                ret_s[q*4+0][r] = 0.f; ret_s[q*4+1][r] = 0.f;
                ret_s[q*4+2][r] = 0.f; ret_s[q*4+3][r] = 0.f;
            }
        }
    }
    __syncthreads();
    {
        int j = t & 63;
        for (int q = t >> 6; q < 32; q += 4){
            float4 u4 = *(const float4*)(U2 + (size_t)(b*SL + jt*64 + j)*RE + q*4);
            pt_s[q*4+0][j] = fmaxf(u4.x + vb_s[q*4+0], 0.f);
            pt_s[q*4+1][j] = fmaxf(u4.y + vb_s[q*4+1], 0.f);
            pt_s[q*4+2][j] = fmaxf(u4.z + vb_s[q*4+2], 0.f);
            pt_s[q*4+3][j] = fmaxf(u4.w + vb_s[q*4+3], 0.f);
        }
    }
    __syncthreads();
    const int mj = (t & 15) * 4;   // j0
    const int nr = (t >> 4) * 4;   // r0
    float accv[4][4];
    #pragma unroll
    for (int i=0;i<4;++i){ accv[i][0]=0.f; accv[i][1]=0.f; accv[i][2]=0.f; accv[i][3]=0.f; }
    #pragma unroll 4
    for (int k = 0; k < RE; ++k){
        float4 aj = *(const float4*)&pt_s[k][mj];
        float4 br = *(const float4*)&ret_s[k][nr];
        float am[4] = {aj.x, aj.y, aj.z, aj.w};
        float bn[4] = {br.x, br.y, br.z, br.w};
        #pragma unroll
        for (int mm = 0; mm < 4; ++mm){
            #pragma unroll
            for (int nn = 0; nn < 4; ++nn)
                accv[mm][nn] += am[mm]*bn[nn];
        }
    }
    float lsum = 0.f;
    #pragma unroll
    for (int nn = 0; nn < 4; ++nn){
        int r = nr + nn;
        if (r < NR){
            const int* gp = gold + (size_t)((b*SL + qi)*NR + r)*SL + jt*64 + mj;
            #pragma unroll
            for (int mm = 0; mm < 4; ++mm){
                float l = accv[mm][nn];
                float g = (float)gp[mm];
                float bce = fmaxf(l, 0.f) - l*g + __logf(1.f + __expf(-fabsf(l)));
                lsum += bce * mk_s[mj + mm];
            }
        }
    }
    #pragma unroll
    for (int off = 32; off > 0; off >>= 1) lsum += __shfl_down(lsum, off);
    if ((t & 63) == 0) red_s[t >> 6] = lsum;
    __syncthreads();
    if (t == 0) atomicAdd(out_sel, red_s[0]+red_s[1]+red_s[2]+red_s[3]);
}

// ---------------------------------------------------------------- finalize
__global__ void finalize_k(const float* __restrict__ accum, float* __restrict__ out)
{
    if (threadIdx.x == 0 && blockIdx.x == 0) out[0] = accum[0] + accum[1] / accum[2];
}

// ---------------------------------------------------------------- launch
extern "C" void kernel_launch(void* const* d_in, const int* in_sizes, int n_in,
                              void* d_out, int out_size, void* d_ws, size_t ws_size,
                              hipStream_t stream)
{
    const int*   tokens    = (const int*)  d_in[0];
    const int*   bio_gold  = (const int*)  d_in[1];
    const int*   sel_gold  = (const int*)  d_in[2];
    // d_in[3] = is_train (unused)
    const float* word_emb  = (const float*)d_in[4];
    const float* rel_emb   = (const float*)d_in[5];
    const float* bio_emb   = (const float*)d_in[6];
    const float* w_ih_f    = (const float*)d_in[7];
    const float* w_hh_f    = (const float*)d_in[8];
    const float* b_ih_f    = (const float*)d_in[9];
    const float* b_hh_f    = (const float*)d_in[10];
    const float* w_ih_b    = (const float*)d_in[11];
    const float* w_hh_b    = (const float*)d_in[12];
    const float* b_ih_b    = (const float*)d_in[13];
    const float* b_hh_b    = (const float*)d_in[14];
    const float* emission_w= (const float*)d_in[15];
    const float* emission_b= (const float*)d_in[16];
    const float* sel_u_w   = (const float*)d_in[17];
    const float* sel_u_b   = (const float*)d_in[18];
    const float* sel_v_w   = (const float*)d_in[19];
    const float* sel_v_b   = (const float*)d_in[20];
    const float* sel_uv_w  = (const float*)d_in[21];
    const float* sel_uv_b  = (const float*)d_in[22];
    const float* crf_trans = (const float*)d_in[23];
    const float* crf_start = (const float*)d_in[24];
    const float* crf_end   = (const float*)d_in[25];
    (void)in_sizes; (void)n_in; (void)out_size; (void)ws_size;

    float* ws     = (float*)d_ws;
    float* emb    = ws;                         // 614400 (dead after xW gemms -> reused for flags)
    float* xwf    = emb    + (size_t)NTOK*ED;   // 4194304
    float* xwb    = xwf    + (size_t)NTOK*G4;   // 4194304
    float* hf_all = xwb    + (size_t)NTOK*G4;   // 1048576
    float* hb_all = hf_all + (size_t)NTOK*HD;   // 1048576
    float* hbuf   = hb_all + (size_t)NTOK*HD;   // 4*NB*HD = 32768
    float* oc     = hbuf   + 4*NB*HD;           // 1179648
    float* emi    = oc     + (size_t)NTOK*OCD;  // 18432
    float* u_     = emi    + (size_t)NTOK*NT;   // 262144
    float* v_     = u_     + (size_t)NTOK*RE;   // 262144
    float* U2     = v_     + (size_t)NTOK*RE;   // 262144
    float* V2     = U2     + (size_t)NTOK*RE;   // 262144
    float* accum  = V2     + (size_t)NTOK*RE;   // [0]=crf, [1]=sel_sum, [2]=msum, [3]=pad

    // barrier flags live in the emb buffer (dead after the xW GEMMs):
    unsigned int* arrive = (unsigned int*)emb;           // SL*256*4 = 131072 uints (padded lines)
    unsigned int* go     = arrive + (size_t)SL*256*4;    // SL*2*4   = 1024 uints

    hipMemsetAsync(accum, 0, 4*sizeof(float), stream);

    gather_emb_k<<<(NTOK*ED + 255)/256, 256, 0, stream>>>(tokens, word_emb, emb);

    dim3 gw(NTOK/128, G4/64);
    gemm_k<128><<<gw, 256, 0, stream>>>(emb, ED, w_ih_f, ED, xwf, G4, G4, ED, b_ih_f, b_hh_f, 0);
    gemm_k<128><<<gw, 256, 0, stream>>>(emb, ED, w_ih_b, ED, xwb, G4, G4, ED, b_ih_b, b_hh_b, 0);

    // emb is dead now; zero the flag region before the cooperative LSTM
    hipMemsetAsync(arrive, 0, ((size_t)SL*256*4 + (size_t)SL*2*4)*sizeof(unsigned int), stream);

    {
        const float *p_xwf = xwf, *p_xwb = xwb, *p_whf = w_hh_f, *p_whb = w_hh_b;
        float *p_hbuf = hbuf, *p_hf = hf_all, *p_hb = hb_all;
        unsigned int *p_ar = arrive, *p_go = go;
        void* args[9] = {&p_xwf, &p_xwb, &p_whf, &p_whb, &p_hbuf, &p_hf, &p_hb, &p_ar, &p_go};
        hipLaunchCooperativeKernel(lstm_k, dim3(256), dim3(256), args, 0u, stream);
    }

    combine_k<<<(NTOK*144 + 255)/256, 256, 0, stream>>>(hf_all, hb_all, bio_gold, bio_emb, oc);

    gemm_k<64><<<dim3(NTOK/64, 1), 256, 0, stream>>>(oc, OCD, emission_w, HD, emi, NT, NT, HD, emission_b, nullptr, 0);
    gemm_k<64><<<dim3(NTOK/64, 2), 256, 0, stream>>>(oc, OCD, sel_u_w, OCD, u_, RE, RE, OCD, sel_u_b, nullptr, 1);
    gemm_k<64><<<dim3(NTOK/64, 2), 256, 0, stream>>>(oc, OCD, sel_v_w, OCD, v_, RE, RE, OCD, sel_v_b, nullptr, 1);
    gemm_k<64><<<dim3(NTOK/64, 2), 256, 0, stream>>>(u_, RE, sel_uv_w,      2*RE, U2, RE, RE, RE, nullptr, nullptr, 0);
    gemm_k<64><<<dim3(NTOK/64, 2), 256, 0, stream>>>(v_, RE, sel_uv_w + RE, 2*RE, V2, RE, RE, RE, nullptr, nullptr, 0);

    crf_k<<<NB, 64, 0, stream>>>(emi, bio_gold, tokens, crf_trans, crf_start, crf_end, accum + 0);
    msum_k<<<1, 256, 0, stream>>>(tokens, accum + 2);
    sel_k<<<dim3(2, SL, NB), 256, 0, stream>>>(U2, V2, sel_uv_b, rel_emb, sel_gold, tokens, accum + 1);

    finalize_k<<<1, 1, 0, stream>>>(accum, (float*)d_out);
}

// Round 3
// 1815.465 us; speedup vs baseline: 1.9778x; 1.9778x over previous
//
#include <hip/hip_runtime.h>
#include <math.h>

// Problem dims
#define NB   16     // batch
#define SL   128    // seq len
#define ED   300    // word emb dim
#define HD   512    // lstm hidden
#define G4   2048   // 4*HD
#define NT   9      // tag count T
#define BE   64     // bio emb dim
#define RE   128    // REL_E
#define NR   50     // R
#define OCD  576    // HD + BE
#define NTOK 2048   // NB*SL

__device__ __forceinline__ float sigf(float x){ return 1.0f/(1.0f + __expf(-x)); }

// ---------------------------------------------------------------- gather emb
__global__ __launch_bounds__(256) void gather_emb_k(const int* __restrict__ tokens,
                                                    const float* __restrict__ word_emb,
                                                    float* __restrict__ emb)
{
    int idx = blockIdx.x*256 + threadIdx.x;
    if (idx < NTOK*ED){
        int row = idx / ED;
        int k = idx - row*ED;
        emb[idx] = word_emb[tokens[row]*ED + k];
    }
}

// ---------------------------------------------------------------- generic fp32 GEMM
// C[m,n] = act( sum_k A[m,k]*B[n,k] + bias1[n] + bias2[n] )
template<int TM>
__global__ __launch_bounds__(256) void gemm_k(const float* __restrict__ A, int lda,
                                              const float* __restrict__ Bm, int ldb,
                                              float* __restrict__ C, int ldc,
                                              int N, int K,
                                              const float* __restrict__ bias1,
                                              const float* __restrict__ bias2,
                                              int do_relu)
{
    constexpr int TR = TM/16;                 // rows per thread (8 or 4)
    __shared__ float As[16][TM+4];            // [k][m]
    __shared__ float Bs[16][68];              // [k][n]
    const int t = threadIdx.x;
    const int m_blk = blockIdx.x * TM;
    const int n_blk = blockIdx.y * 64;
    const int tm = (t >> 4) * TR;
    const int tn = (t & 15) * 4;
    float acc[TR][4];
    #pragma unroll
    for (int i=0;i<TR;++i){ acc[i][0]=0.f; acc[i][1]=0.f; acc[i][2]=0.f; acc[i][3]=0.f; }

    const int kc = (K + 15) >> 4;
    for (int ck = 0; ck < kc; ++ck){
        const int k0 = ck << 4;
        __syncthreads();
        #pragma unroll
        for (int it = 0; it < TM/64; ++it){
            int task = t + it*256;
            int m = task >> 2, q = task & 3;
            int kk = k0 + q*4;
            float4 v = make_float4(0.f,0.f,0.f,0.f);
            const float* ap = A + (size_t)(m_blk + m)*lda + kk;
            if (kk + 3 < K) v = *(const float4*)ap;
            else {
                if (kk   < K) v.x = ap[0];
                if (kk+1 < K) v.y = ap[1];
                if (kk+2 < K) v.z = ap[2];
            }
            As[q*4+0][m] = v.x; As[q*4+1][m] = v.y; As[q*4+2][m] = v.z; As[q*4+3][m] = v.w;
        }
        {
            int n = t >> 2, q = t & 3;
            int kk = k0 + q*4;
            int gn = n_blk + n;
            float4 v = make_float4(0.f,0.f,0.f,0.f);
            if (gn < N){
                const float* bp = Bm + (size_t)gn*ldb + kk;
                if (kk + 3 < K) v = *(const float4*)bp;
                else {
                    if (kk   < K) v.x = bp[0];
                    if (kk+1 < K) v.y = bp[1];
                    if (kk+2 < K) v.z = bp[2];
                }
            }
            Bs[q*4+0][n] = v.x; Bs[q*4+1][n] = v.y; Bs[q*4+2][n] = v.z; Bs[q*4+3][n] = v.w;
        }
        __syncthreads();
        #pragma unroll
        for (int k = 0; k < 16; ++k){
            float4 b4 = *(const float4*)&Bs[k][tn];
            float bn[4] = {b4.x, b4.y, b4.z, b4.w};
            #pragma unroll
            for (int i = 0; i < TR/4; ++i){
                float4 a4 = *(const float4*)&As[k][tm + i*4];
                float am[4] = {a4.x, a4.y, a4.z, a4.w};
                #pragma unroll
                for (int mm = 0; mm < 4; ++mm){
                    #pragma unroll
                    for (int nn = 0; nn < 4; ++nn)
                        acc[i*4+mm][nn] += am[mm]*bn[nn];
                }
            }
        }
    }
    float bv[4];
    #pragma unroll
    for (int nn=0;nn<4;++nn){
        int gn = n_blk + tn + nn;
        float bb = 0.f;
        if (gn < N){
            if (bias1) bb += bias1[gn];
            if (bias2) bb += bias2[gn];
        }
        bv[nn] = bb;
    }
    bool vec = ((ldc & 3) == 0) && (n_blk + tn + 3 < N);
    #pragma unroll
    for (int mm = 0; mm < TR; ++mm){
        int gm = m_blk + tm + mm;
        float r0 = acc[mm][0] + bv[0];
        float r1 = acc[mm][1] + bv[1];
        float r2 = acc[mm][2] + bv[2];
        float r3 = acc[mm][3] + bv[3];
        if (do_relu){ r0=fmaxf(r0,0.f); r1=fmaxf(r1,0.f); r2=fmaxf(r2,0.f); r3=fmaxf(r3,0.f); }
        if (vec){
            *(float4*)(C + (size_t)gm*ldc + n_blk + tn) = make_float4(r0,r1,r2,r3);
        } else {
            int gn = n_blk + tn;
            if (gn   < N) C[(size_t)gm*ldc + gn  ] = r0;
            if (gn+1 < N) C[(size_t)gm*ldc + gn+1] = r1;
            if (gn+2 < N) C[(size_t)gm*ldc + gn+2] = r2;
            if (gn+3 < N) C[(size_t)gm*ldc + gn+3] = r3;
        }
    }
}

// ---------------------------------------------------------------- team-parallel LSTM
// 8 independent teams of 32 wgs; team = (dir = team&1, batches [(team>>1)*4, +4)).
// No cross-team communication (batches are independent sequences). Within a team:
// wg rank owns hidden units [rank*16, rank*16+16) (64 gate rows); its 128KB weight
// slice lives in VGPRs (loaded once). Per step: stage 8KB team-h from LLC (relaxed
// agent atomics only -- no release/acquire, no L2 writeback/invalidate storms, the
// R1/R2 suspect), compute 64 rows x 4 batches with wave-uniform (broadcast) LDS h
// reads, activation for 16 hidden x 4 batches, store h_next to LLC, then a relaxed
// 32-participant flag barrier (ordering = __syncthreads' vmcnt(0) drain + LLC being
// the single coherence point for the relaxed sc0/sc1 ops).
__global__ __launch_bounds__(256) void lstm_k(const float* __restrict__ xwf,
                                              const float* __restrict__ xwb,
                                              const float* __restrict__ whhf,
                                              const float* __restrict__ whhb,
                                              float* __restrict__ hteam,          // [8][2][4*HD]
                                              float* __restrict__ hf_all,
                                              float* __restrict__ hb_all,
                                              unsigned int* __restrict__ arrive,  // [8][SL][32]
                                              unsigned int* __restrict__ gof)     // [8][SL][32]
{
    __shared__ __align__(16) float h_s[4*HD];      // 8 KB  [b][512]
    __shared__ __align__(16) float part[4*64*4];   // 4 KB  [kq][row][b]
    __shared__ float gates_s[64*4];                // [row][b]
    __shared__ float cst[64];                      // [b*16 + hl]
    const int wg   = blockIdx.x;
    const int team = wg >> 5;
    const int rank = wg & 31;
    const int d    = team & 1;
    const int b0   = (team >> 1) * 4;
    const int t    = threadIdx.x;
    const int kq   = t >> 6;                       // k-quarter (== wave id)
    const int rl   = t & 63;                       // local gate row 0..63
    const int grow = (rl >> 4)*HD + rank*16 + (rl & 15);   // global gate row
    const float* whh = d ? whhb : whhf;
    const float* xw  = d ? xwb  : xwf;
    float* hall      = d ? hb_all : hf_all;
    float* hT        = hteam + (size_t)team*2*(4*HD);

    // ---- one-time: weight slice into registers (32 float4 = 128 VGPRs) ----
    float4 w[32];
    {
        const float* wp = whh + (size_t)grow*HD + kq*128;
        #pragma unroll
        for (int q=0;q<32;++q) w[q] = *(const float4*)(wp + q*4);
    }
    // reduce mapping: t -> (row, batch)
    const int rrow = t >> 2, rb = t & 3;
    const int growr = (rrow >> 4)*HD + rank*16 + (rrow & 15);
    // activation mapping: t<64 -> (hidden-local, batch)
    const int ahl = t & 15, ab = t >> 4;
    const int hidx_a = rank*16 + ahl;

    if (t < 64) cst[t] = 0.f;
    // zero the initial-parity h slab ourselves (all team wgs race-write identical 0s)
    for (int i = t; i < 4*HD; i += 256)
        __hip_atomic_store(&hT[i], 0.f, __ATOMIC_RELAXED, __HIP_MEMORY_SCOPE_AGENT);
    __syncthreads();   // drains vmcnt -> our zeros are at LLC before we read them

    int par = 0;
    for (int s = 0; s < SL; ++s){
        // ---- 1. stage team h into LDS (relaxed LLC loads) ----
        {
            const unsigned long long* src = (const unsigned long long*)(hT + par*(4*HD));
            unsigned long long* dst = (unsigned long long*)h_s;
            #pragma unroll
            for (int i = 0; i < 4; ++i)
                dst[i*256 + t] = __hip_atomic_load(&src[i*256 + t], __ATOMIC_RELAXED, __HIP_MEMORY_SCOPE_AGENT);
        }
        const int tx = d ? (SL-1 - s) : s;
        __syncthreads();
        // ---- 2. partial dots: row rl, k-quarter kq, all 4 batches ----
        {
            float a0=0.f, a1=0.f, a2=0.f, a3=0.f;
            const float* hb_ = h_s + kq*128;       // wave-uniform base -> LDS broadcast
            #pragma unroll 8
            for (int q = 0; q < 32; ++q){
                float4 wq = w[q];
                float4 h0 = *(const float4*)(hb_ + 0*HD + q*4);
                float4 h1 = *(const float4*)(hb_ + 1*HD + q*4);
                float4 h2 = *(const float4*)(hb_ + 2*HD + q*4);
                float4 h3 = *(const float4*)(hb_ + 3*HD + q*4);
                a0 += wq.x*h0.x + wq.y*h0.y + wq.z*h0.z + wq.w*h0.w;
                a1 += wq.x*h1.x + wq.y*h1.y + wq.z*h1.z + wq.w*h1.w;
                a2 += wq.x*h2.x + wq.y*h2.y + wq.z*h2.z + wq.w*h2.w;
                a3 += wq.x*h3.x + wq.y*h3.y + wq.z*h3.z + wq.w*h3.w;
            }
            *(float4*)&part[(kq*64 + rl)*4] = make_float4(a0,a1,a2,a3);
        }
        __syncthreads();
        // ---- 3. reduce k-quarters + add xW (biases folded into xW) ----
        {
            float gsum = part[(0*64 + rrow)*4 + rb] + part[(1*64 + rrow)*4 + rb]
                       + part[(2*64 + rrow)*4 + rb] + part[(3*64 + rrow)*4 + rb];
            gsum += xw[(size_t)((b0 + rb)*SL + tx)*G4 + growr];
            gates_s[rrow*4 + rb] = gsum;
        }
        __syncthreads();
        // ---- 4. activation: 16 hidden x 4 batches ----
        if (t < 64){
            float gi = gates_s[((0*16) + ahl)*4 + ab];
            float gf = gates_s[((1*16) + ahl)*4 + ab];
            float gc = gates_s[((2*16) + ahl)*4 + ab];
            float gov = gates_s[((3*16) + ahl)*4 + ab];
            float cp = cst[t];
            float cn = sigf(gf)*cp + sigf(gi)*tanhf(gc);
            float hn = sigf(gov)*tanhf(cn);
            cst[t] = cn;
            __hip_atomic_store(&hT[(par^1)*(4*HD) + ab*HD + hidx_a], hn,
                               __ATOMIC_RELAXED, __HIP_MEMORY_SCOPE_AGENT);
            hall[(size_t)((b0 + ab)*SL + tx)*HD + hidx_a] = hn;
        }
        __syncthreads();   // every wave drains its vmcnt -> h_next is at LLC
        // ---- 5. relaxed-only 32-wg team barrier ----
        if (s < SL-1){
            const size_t fb = (size_t)(team*SL + s)*32;
            if (t == 0)
                __hip_atomic_store(&arrive[fb + rank], 1u, __ATOMIC_RELAXED, __HIP_MEMORY_SCOPE_AGENT);
            if (rank == 0){
                if (t < 64){
                    const int fi = t & 31;
                    for (;;){
                        unsigned int f = __hip_atomic_load(&arrive[fb + fi], __ATOMIC_RELAXED, __HIP_MEMORY_SCOPE_AGENT);
                        if (__all(f != 0u)) break;
                        __builtin_amdgcn_s_sleep(2);
                    }
                    if (t == 0)
                        __hip_atomic_store(&gof[fb], 1u, __ATOMIC_RELAXED, __HIP_MEMORY_SCOPE_AGENT);
                }
            } else {
                if (t == 0){
                    while (__hip_atomic_load(&gof[fb], __ATOMIC_RELAXED, __HIP_MEMORY_SCOPE_AGENT) == 0u)
                        __builtin_amdgcn_s_sleep(2);
                }
            }
            __syncthreads();
        }
        par ^= 1;
    }
}

// ---------------------------------------------------------------- combine o | bio_emb
__global__ __launch_bounds__(256) void combine_k(const float* __restrict__ hf,
                                                 const float* __restrict__ hb,
                                                 const int* __restrict__ bio_gold,
                                                 const float* __restrict__ bio_emb,
                                                 float* __restrict__ oc)
{
    int idx = blockIdx.x*256 + threadIdx.x;      // float4 index over NTOK*144
    if (idx >= NTOK*144) return;
    int row = idx / 144;
    int c4 = (idx - row*144) * 4;
    float4 v;
    if (c4 < HD){
        float4 a = *(const float4*)(hf + (size_t)row*HD + c4);
        float4 b = *(const float4*)(hb + (size_t)row*HD + c4);
        v = make_float4(0.5f*(a.x+b.x), 0.5f*(a.y+b.y), 0.5f*(a.z+b.z), 0.5f*(a.w+b.w));
    } else {
        int bg = bio_gold[row];
        v = *(const float4*)(bio_emb + bg*BE + (c4 - HD));
    }
    *(float4*)(oc + (size_t)row*OCD + c4) = v;
}

// ---------------------------------------------------------------- CRF NLL
__global__ __launch_bounds__(64) void crf_k(const float* __restrict__ emi,
                                            const int* __restrict__ tags,
                                            const int* __restrict__ tokens,
                                            const float* __restrict__ trans,
                                            const float* __restrict__ startv,
                                            const float* __restrict__ endv,
                                            float* __restrict__ out_crf)
{
    __shared__ float al[16];
    const int b = blockIdx.x, lane = threadIdx.x;
    unsigned long long m0 = __ballot(tokens[b*SL + lane] != 0);
    unsigned long long m1 = __ballot(tokens[b*SL + 64 + lane] != 0);
    const int len = __popcll(m0) + __popcll(m1);
    float npart = 0.f;
    #pragma unroll
    for (int half = 0; half < 2; ++half){
        int tt = lane + half*64;
        if (tt >= 1 && tt < len){
            int tp = tags[b*SL + tt - 1], tc = tags[b*SL + tt];
            npart += trans[tp*NT + tc] + emi[(size_t)(b*SL + tt)*NT + tc];
        }
    }
    #pragma unroll
    for (int off = 32; off > 0; off >>= 1) npart += __shfl_down(npart, off);
    float tr[NT]; float alpha = -1e30f;
    if (lane < NT){
        #pragma unroll
        for (int i = 0; i < NT; ++i) tr[i] = trans[i*NT + lane];
        alpha = startv[lane] + emi[(size_t)(b*SL)*NT + lane];
    }
    for (int tt = 1; tt < SL; ++tt){
        if (lane < NT) al[lane] = alpha;
        __syncthreads();
        if (lane < NT && tt < len){
            float mx = -1e30f;
            #pragma unroll
            for (int i = 0; i < NT; ++i) mx = fmaxf(mx, al[i] + tr[i]);
            float se = 0.f;
            #pragma unroll
            for (int i = 0; i < NT; ++i) se += __expf(al[i] + tr[i] - mx);
            alpha = mx + __logf(se) + emi[(size_t)(b*SL + tt)*NT + lane];
        }
        __syncthreads();
    }
    if (lane < NT) al[lane] = alpha + endv[lane];
    __syncthreads();
    if (lane == 0){
        float mx = -1e30f;
        for (int i = 0; i < NT; ++i) mx = fmaxf(mx, al[i]);
        float se = 0.f;
        for (int i = 0; i < NT; ++i) se += __expf(al[i] - mx);
        float den = mx + __logf(se);
        int t0g = tags[b*SL];
        float num = startv[t0g] + emi[(size_t)(b*SL)*NT + t0g] + npart;
        num += endv[tags[b*SL + len - 1]];
        atomicAdd(out_crf, -(num - den) * (1.0f/16.0f));
    }
}

// ---------------------------------------------------------------- token count
__global__ __launch_bounds__(256) void msum_k(const int* __restrict__ tokens, float* __restrict__ out_m)
{
    __shared__ int rr[4];
    int t = threadIdx.x;
    int cnt = 0;
    for (int i = t; i < NTOK; i += 256) cnt += (tokens[i] != 0) ? 1 : 0;
    #pragma unroll
    for (int off = 32; off > 0; off >>= 1) cnt += __shfl_down(cnt, off);
    if ((t & 63) == 0) rr[t >> 6] = cnt;
    __syncthreads();
    if (t == 0) out_m[0] = (float)(rr[0]+rr[1]+rr[2]+rr[3]);
}

// ---------------------------------------------------------------- fused uv->logits->BCE
__global__ __launch_bounds__(256) void sel_k(const float* __restrict__ U2,
                                             const float* __restrict__ V2,
                                             const float* __restrict__ uvb,
                                             const float* __restrict__ rel_emb,
                                             const int* __restrict__ gold,
                                             const int* __restrict__ tokens,
                                             float* __restrict__ out_sel)
{
    __shared__ float ret_s[RE][52];   // [k][r]
    __shared__ float pt_s[RE][68];    // [k][j]
    __shared__ float vb_s[RE];
    __shared__ float mk_s[64];
    __shared__ float red_s[4];
    const int jt = blockIdx.x, qi = blockIdx.y, b = blockIdx.z;
    const int t = threadIdx.x;
    if (tokens[b*SL + qi] == 0) return;   // pm row entirely zero
    if (t < 32){
        float4 v4 = *(const float4*)(V2 + (size_t)(b*SL + qi)*RE + t*4);
        float4 b4 = *(const float4*)(uvb + t*4);
        vb_s[t*4+0] = v4.x + b4.x; vb_s[t*4+1] = v4.y + b4.y;
        vb_s[t*4+2] = v4.z + b4.z; vb_s[t*4+3] = v4.w + b4.w;
    }
    if (t < 64) mk_s[t] = (tokens[b*SL + jt*64 + t] != 0) ? 1.f : 0.f;
    {
        int r = t & 63;
        for (int q = t >> 6; q < 32; q += 4){
            if (r < NR){
                float4 e4 = *(const float4*)(rel_emb + (size_t)r*RE + q*4);
                ret_s[q*4+0][r] = e4.x; ret_s[q*4+1][r] = e4.y;
                ret_s[q*4+2][r] = e4.z; ret_s[q*4+3][r] = e4.w;
            } else if (r < 64){
                ret_s[q*4+0][r] = 0.f; ret_s[q*4+1][r] = 0.f;
                ret_s[q*4+2][r] = 0.f; ret_s[q*4+3][r] = 0.f;
            }
        }
    }
    __syncthreads();
    {
        int j = t & 63;
        for (int q = t >> 6; q < 32; q += 4){
            float4 u4 = *(const float4*)(U2 + (size_t)(b*SL + jt*64 + j)*RE + q*4);
            pt_s[q*4+0][j] = fmaxf(u4.x + vb_s[q*4+0], 0.f);
            pt_s[q*4+1][j] = fmaxf(u4.y + vb_s[q*4+1], 0.f);
            pt_s[q*4+2][j] = fmaxf(u4.z + vb_s[q*4+2], 0.f);
            pt_s[q*4+3][j] = fmaxf(u4.w + vb_s[q*4+3], 0.f);
        }
    }
    __syncthreads();
    const int mj = (t & 15) * 4;   // j0
    const int nr = (t >> 4) * 4;   // r0
    float accv[4][4];
    #pragma unroll
    for (int i=0;i<4;++i){ accv[i][0]=0.f; accv[i][1]=0.f; accv[i][2]=0.f; accv[i][3]=0.f; }
    #pragma unroll 4
    for (int k = 0; k < RE; ++k){
        float4 aj = *(const float4*)&pt_s[k][mj];
        float4 br = *(const float4*)&ret_s[k][nr];
        float am[4] = {aj.x, aj.y, aj.z, aj.w};
        float bn[4] = {br.x, br.y, br.z, br.w};
        #pragma unroll
        for (int mm = 0; mm < 4; ++mm){
            #pragma unroll
            for (int nn = 0; nn < 4; ++nn)
                accv[mm][nn] += am[mm]*bn[nn];
        }
    }
    float lsum = 0.f;
    #pragma unroll
    for (int nn = 0; nn < 4; ++nn){
        int r = nr + nn;
        if (r < NR){
            const int* gp = gold + (size_t)((b*SL + qi)*NR + r)*SL + jt*64 + mj;
            #pragma unroll
            for (int mm = 0; mm < 4; ++mm){
                float l = accv[mm][nn];
                float g = (float)gp[mm];
                float bce = fmaxf(l, 0.f) - l*g + __logf(1.f + __expf(-fabsf(l)));
                lsum += bce * mk_s[mj + mm];
            }
        }
    }
    #pragma unroll
    for (int off = 32; off > 0; off >>= 1) lsum += __shfl_down(lsum, off);
    if ((t & 63) == 0) red_s[t >> 6] = lsum;
    __syncthreads();
    if (t == 0) atomicAdd(out_sel, red_s[0]+red_s[1]+red_s[2]+red_s[3]);
}

// ---------------------------------------------------------------- finalize
__global__ void finalize_k(const float* __restrict__ accum, float* __restrict__ out)
{
    if (threadIdx.x == 0 && blockIdx.x == 0) out[0] = accum[0] + accum[1] / accum[2];
}

// ---------------------------------------------------------------- launch
extern "C" void kernel_launch(void* const* d_in, const int* in_sizes, int n_in,
                              void* d_out, int out_size, void* d_ws, size_t ws_size,
                              hipStream_t stream)
{
    const int*   tokens    = (const int*)  d_in[0];
    const int*   bio_gold  = (const int*)  d_in[1];
    const int*   sel_gold  = (const int*)  d_in[2];
    // d_in[3] = is_train (unused)
    const float* word_emb  = (const float*)d_in[4];
    const float* rel_emb   = (const float*)d_in[5];
    const float* bio_emb   = (const float*)d_in[6];
    const float* w_ih_f    = (const float*)d_in[7];
    const float* w_hh_f    = (const float*)d_in[8];
    const float* b_ih_f    = (const float*)d_in[9];
    const float* b_hh_f    = (const float*)d_in[10];
    const float* w_ih_b    = (const float*)d_in[11];
    const float* w_hh_b    = (const float*)d_in[12];
    const float* b_ih_b    = (const float*)d_in[13];
    const float* b_hh_b    = (const float*)d_in[14];
    const float* emission_w= (const float*)d_in[15];
    const float* emission_b= (const float*)d_in[16];
    const float* sel_u_w   = (const float*)d_in[17];
    const float* sel_u_b   = (const float*)d_in[18];
    const float* sel_v_w   = (const float*)d_in[19];
    const float* sel_v_b   = (const float*)d_in[20];
    const float* sel_uv_w  = (const float*)d_in[21];
    const float* sel_uv_b  = (const float*)d_in[22];
    const float* crf_trans = (const float*)d_in[23];
    const float* crf_start = (const float*)d_in[24];
    const float* crf_end   = (const float*)d_in[25];
    (void)in_sizes; (void)n_in; (void)out_size; (void)ws_size;

    float* ws     = (float*)d_ws;
    float* emb    = ws;                         // 614400 (dead after xW gemms -> reused below)
    float* xwf    = emb    + (size_t)NTOK*ED;   // 4194304
    float* xwb    = xwf    + (size_t)NTOK*G4;   // 4194304
    float* hf_all = xwb    + (size_t)NTOK*G4;   // 1048576
    float* hb_all = hf_all + (size_t)NTOK*HD;   // 1048576
    float* oc     = hb_all + (size_t)NTOK*HD;   // 1179648
    float* emi    = oc     + (size_t)NTOK*OCD;  // 18432
    float* u_     = emi    + (size_t)NTOK*NT;   // 262144
    float* v_     = u_     + (size_t)NTOK*RE;   // 262144
    float* U2     = v_     + (size_t)NTOK*RE;   // 262144
    float* V2     = U2     + (size_t)NTOK*RE;   // 262144
    float* accum  = V2     + (size_t)NTOK*RE;   // [0]=crf, [1]=sel_sum, [2]=msum, [3]=pad

    // LSTM team-sync structures live in the emb buffer (dead after the xW GEMMs):
    float*        hteam  = emb;                                  // 8*2*2048   = 32768 floats
    unsigned int* arrive = (unsigned int*)(hteam + 8*2*(4*HD));  // 8*128*32   = 32768 uints
    unsigned int* gof    = arrive + 8*SL*32;                     // 8*128*32   = 32768 uints

    hipMemsetAsync(accum, 0, 4*sizeof(float), stream);

    gather_emb_k<<<(NTOK*ED + 255)/256, 256, 0, stream>>>(tokens, word_emb, emb);

    dim3 gw(NTOK/128, G4/64);
    gemm_k<128><<<gw, 256, 0, stream>>>(emb, ED, w_ih_f, ED, xwf, G4, G4, ED, b_ih_f, b_hh_f, 0);
    gemm_k<128><<<gw, 256, 0, stream>>>(emb, ED, w_ih_b, ED, xwb, G4, G4, ED, b_ih_b, b_hh_b, 0);

    // emb is dead now; zero hteam + flags before the cooperative LSTM
    hipMemsetAsync(hteam, 0, (8*2*(4*HD) + 2*8*SL*32)*sizeof(unsigned int), stream);

    {
        const float *p_xwf = xwf, *p_xwb = xwb, *p_whf = w_hh_f, *p_whb = w_hh_b;
        float *p_ht = hteam, *p_hf = hf_all, *p_hb = hb_all;
        unsigned int *p_ar = arrive, *p_go = gof;
        void* args[9] = {&p_xwf, &p_xwb, &p_whf, &p_whb, &p_ht, &p_hf, &p_hb, &p_ar, &p_go};
        hipLaunchCooperativeKernel(lstm_k, dim3(256), dim3(256), args, 0u, stream);
    }

    combine_k<<<(NTOK*144 + 255)/256, 256, 0, stream>>>(hf_all, hb_all, bio_gold, bio_emb, oc);

    gemm_k<64><<<dim3(NTOK/64, 1), 256, 0, stream>>>(oc, OCD, emission_w, HD, emi, NT, NT, HD, emission_b, nullptr, 0);
    gemm_k<64><<<dim3(NTOK/64, 2), 256, 0, stream>>>(oc, OCD, sel_u_w, OCD, u_, RE, RE, OCD, sel_u_b, nullptr, 1);
    gemm_k<64><<<dim3(NTOK/64, 2), 256, 0, stream>>>(oc, OCD, sel_v_w, OCD, v_, RE, RE, OCD, sel_v_b, nullptr, 1);
    gemm_k<64><<<dim3(NTOK/64, 2), 256, 0, stream>>>(u_, RE, sel_uv_w,      2*RE, U2, RE, RE, RE, nullptr, nullptr, 0);
    gemm_k<64><<<dim3(NTOK/64, 2), 256, 0, stream>>>(v_, RE, sel_uv_w + RE, 2*RE, V2, RE, RE, RE, nullptr, nullptr, 0);

    crf_k<<<NB, 64, 0, stream>>>(emi, bio_gold, tokens, crf_trans, crf_start, crf_end, accum + 0);
    msum_k<<<1, 256, 0, stream>>>(tokens, accum + 2);
    sel_k<<<dim3(2, SL, NB), 256, 0, stream>>>(U2, V2, sel_uv_b, rel_emb, sel_gold, tokens, accum + 1);

    finalize_k<<<1, 1, 0, stream>>>(accum, (float*)d_out);
}